// Round 2
// 481.332 us; speedup vs baseline: 1.0255x; 1.0255x over previous
//
#include <hip/hip_runtime.h>
#include <hip/hip_fp16.h>
#include <math.h>

#define D 128

__device__ __forceinline__ float sigmoidf_(float x) { return 1.f / (1.f + __expf(-x)); }

__device__ __forceinline__ float4 pack8_to_half8(const float* xf) {
    __half2 hh[4];
    hh[0] = __floats2half2_rn(xf[0], xf[1]);
    hh[1] = __floats2half2_rn(xf[2], xf[3]);
    hh[2] = __floats2half2_rn(xf[4], xf[5]);
    hh[3] = __floats2half2_rn(xf[6], xf[7]);
    return *(float4*)hh;
}

// ---------------- fused prep: Wc | seg_off | b_sum,h1,c1 ----------------
__global__ void prep_kernel(const float* __restrict__ W_ih, const float* __restrict__ W_hh,
                            const float* __restrict__ b_ih, const float* __restrict__ b_hh,
                            const int* __restrict__ idx, int N, int G,
                            float* __restrict__ Wc, int* __restrict__ seg_off,
                            float* __restrict__ b_sum, float* __restrict__ h1,
                            float* __restrict__ c1) {
    int b = blockIdx.x, t = threadIdx.x;
    if (b < 256) {
        int i = b * 256 + t;
        int j = i >> 7, k = i & (D - 1);
        Wc[i] = W_ih[(size_t)j * (2 * D) + k] + W_hh[i];
    } else if (b < 273) {
        int g = (b - 256) * 256 + t;
        if (g <= G) {
            int lo = 0, hi = N;
            while (lo < hi) {
                int mid = (lo + hi) >> 1;
                if (idx[mid] < g) lo = mid + 1; else hi = mid;
            }
            seg_off[g] = lo;
        }
    } else {
        for (int i = t; i < 4 * D; i += 256) b_sum[i] = b_ih[i] + b_hh[i];
        if (t < D) {
            float bi = b_ih[t] + b_hh[t];
            float bg = b_ih[2 * D + t] + b_hh[2 * D + t];
            float bo = b_ih[3 * D + t] + b_hh[3 * D + t];
            float c = sigmoidf_(bi) * tanhf(bg);
            c1[t] = c;
            h1[t] = sigmoidf_(bo) * tanhf(c);
        }
    }
}

// ---------------- attention step 1: fp32 x in, fp16 xh out (fused convert) ---------
// lane = qg*16 + c: group qg owns rows base+qg and base+4+qg, lane c covers cols
// 8c..8c+7. Scores/acc in fp32 from fp32 x; each loaded row chunk is also packed to
// fp16 and stored to xh for steps 2,3. Rows are partitioned by segment across blocks,
// so each xh row is written by exactly one block (clamped dup rows rewrite identical
// bytes: benign).
__global__ __launch_bounds__(256) void attn_first_kernel(
    const float* __restrict__ x, __half* __restrict__ xh,
    const int* __restrict__ seg_off, const float* __restrict__ q,
    float* __restrict__ r_out, int G) {
    int g = blockIdx.x;
    if (g >= G) return;
    int tid = threadIdx.x;
    int wave = tid >> 6, lane = tid & 63;
    int qg = lane >> 4;
    int c = lane & 15;

    __shared__ float sm[4], ss[4];
    __shared__ float sacc[4][D];

    int start = seg_off[g], end = seg_off[g + 1];
    int count = end - start;
    int chunk = (count + 3) >> 2;
    int wsr = start + wave * chunk;
    int wer = min(wsr + chunk, end);

    const float4* x4 = (const float4*)x;   // 32 float4 per fp32 row
    float4* xh4 = (float4*)xh;             // 16 float4 per fp16 row
    float4 q0 = *(const float4*)&q[8 * c];
    float4 q1 = *(const float4*)&q[8 * c + 4];

    float m = -INFINITY, s = 0.f;
    float acc[8] = {0.f, 0.f, 0.f, 0.f, 0.f, 0.f, 0.f, 0.f};

    if (wsr < wer) {
        int last = wer - 1;
        for (int base = wsr; base < wer; base += 8) {
            int r0 = min(base + qg, last);
            int r1 = min(base + 4 + qg, last);
            float4 f00 = x4[(size_t)r0 * 32 + 2 * c];
            float4 f01 = x4[(size_t)r0 * 32 + 2 * c + 1];
            float4 f10 = x4[(size_t)r1 * 32 + 2 * c];
            float4 f11 = x4[(size_t)r1 * 32 + 2 * c + 1];
            float xf0[8] = {f00.x, f00.y, f00.z, f00.w, f01.x, f01.y, f01.z, f01.w};
            float xf1[8] = {f10.x, f10.y, f10.z, f10.w, f11.x, f11.y, f11.z, f11.w};

            xh4[(size_t)r0 * 16 + c] = pack8_to_half8(xf0);
            xh4[(size_t)r1 * 16 + c] = pack8_to_half8(xf1);

            float p0 = xf0[0] * q0.x + xf0[1] * q0.y + xf0[2] * q0.z + xf0[3] * q0.w
                     + xf0[4] * q1.x + xf0[5] * q1.y + xf0[6] * q1.z + xf0[7] * q1.w;
            float p1 = xf1[0] * q0.x + xf1[1] * q0.y + xf1[2] * q0.z + xf1[3] * q0.w
                     + xf1[4] * q1.x + xf1[5] * q1.y + xf1[6] * q1.z + xf1[7] * q1.w;
#pragma unroll
            for (int off = 1; off < 16; off <<= 1) {
                p0 += __shfl_xor(p0, off);
                p1 += __shfl_xor(p1, off);
            }
            float p0a = __shfl_xor(p0, 16), p0b = __shfl_xor(p0, 32), p0c = __shfl_xor(p0a, 32);
            float p1a = __shfl_xor(p1, 16), p1b = __shfl_xor(p1, 32), p1c = __shfl_xor(p1a, 32);
            float s00 = (base + qg       < wer) ? p0  : -INFINITY;
            float s01 = (base + (qg ^ 1) < wer) ? p0a : -INFINITY;
            float s02 = (base + (qg ^ 2) < wer) ? p0b : -INFINITY;
            float s03 = (base + (qg ^ 3) < wer) ? p0c : -INFINITY;
            float s10 = (base + 4 + qg       < wer) ? p1  : -INFINITY;
            float s11 = (base + 4 + (qg ^ 1) < wer) ? p1a : -INFINITY;
            float s12 = (base + 4 + (qg ^ 2) < wer) ? p1b : -INFINITY;
            float s13 = (base + 4 + (qg ^ 3) < wer) ? p1c : -INFINITY;

            float mn = fmaxf(fmaxf(fmaxf(s00, s01), fmaxf(s02, s03)),
                             fmaxf(fmaxf(s10, s11), fmaxf(s12, s13)));
            mn = fmaxf(m, mn);
            float al = __expf(m - mn);
            float w00 = __expf(s00 - mn), w01 = __expf(s01 - mn);
            float w02 = __expf(s02 - mn), w03 = __expf(s03 - mn);
            float w10 = __expf(s10 - mn), w11 = __expf(s11 - mn);
            float w12 = __expf(s12 - mn), w13 = __expf(s13 - mn);
            float sg = (w00 + w01) + (w02 + w03) + ((w10 + w11) + (w12 + w13));
            s = s * al + sg;
#pragma unroll
            for (int j = 0; j < 8; ++j)
                acc[j] = acc[j] * al + w00 * xf0[j] + w10 * xf1[j];
            m = mn;
        }
    }
#pragma unroll
    for (int j = 0; j < 8; ++j) {
        acc[j] += __shfl_xor(acc[j], 16);
        acc[j] += __shfl_xor(acc[j], 32);
    }
    if (lane == 0) { sm[wave] = m; ss[wave] = s; }
    if (qg == 0) {
#pragma unroll
        for (int j = 0; j < 8; ++j) sacc[wave][8 * c + j] = acc[j];
    }
    __syncthreads();

    if (tid < D) {
        float m0 = sm[0], m1 = sm[1], m2 = sm[2], m3 = sm[3];
        float mstar = fmaxf(fmaxf(m0, m1), fmaxf(m2, m3));
        float r = 0.f;
        if (mstar > -INFINITY) {
            float e0 = __expf(m0 - mstar), e1 = __expf(m1 - mstar);
            float e2 = __expf(m2 - mstar), e3 = __expf(m3 - mstar);
            float stot = ss[0] * e0 + ss[1] * e1 + ss[2] * e2 + ss[3] * e3;
            float at = sacc[0][tid] * e0 + sacc[1][tid] * e1
                     + sacc[2][tid] * e2 + sacc[3][tid] * e3;
            r = at / fmaxf(stot, 1e-16f);
        }
        r_out[(size_t)g * D + tid] = r;
    }
}

// ---------------- attention steps 2,3 with fused LSTM-cell prologue ----------------
// Block g first computes its own row's (h,c) from gates+c_prev (128 threads), stages
// q=h in LDS, writes h (and optionally c) to global, then runs the fp16 attention.
__global__ __launch_bounds__(256) void attn_cell_kernel(
    const __half* __restrict__ xh, const int* __restrict__ seg_off,
    const float* __restrict__ gates,
    const float* __restrict__ c_prev, int c_stride,
    float* __restrict__ c_out,
    float* __restrict__ h_out, int h_stride,
    float* __restrict__ r_out, int r_stride, int G) {
    int g = blockIdx.x;
    if (g >= G) return;
    int tid = threadIdx.x;
    int wave = tid >> 6, lane = tid & 63;
    int qg = lane >> 4;
    int c = lane & 15;

    __shared__ float sm[4], ss[4];
    __shared__ float sacc[4][D];
    __shared__ float qsh[D];

    // --- fused LSTM cell for this block's row ---
    if (tid < D) {
        const float* grow = gates + (size_t)g * 512;
        float ig = grow[tid];
        float fg = grow[D + tid];
        float gg = grow[2 * D + tid];
        float og = grow[3 * D + tid];
        float cp = c_prev[(size_t)g * c_stride + tid];
        float cc = sigmoidf_(fg) * cp + sigmoidf_(ig) * tanhf(gg);
        float hh = sigmoidf_(og) * tanhf(cc);
        if (c_out) c_out[(size_t)g * D + tid] = cc;
        h_out[(size_t)g * h_stride + tid] = hh;
        qsh[tid] = hh;
    }
    __syncthreads();

    int start = seg_off[g], end = seg_off[g + 1];
    int count = end - start;
    int chunk = (count + 3) >> 2;
    int wsr = start + wave * chunk;
    int wer = min(wsr + chunk, end);

    const float4* x4 = (const float4*)xh;  // 16 float4 per fp16 row
    float4 q0 = *(const float4*)&qsh[8 * c];
    float4 q1 = *(const float4*)&qsh[8 * c + 4];

    float m = -INFINITY, s = 0.f;
    float acc[8] = {0.f, 0.f, 0.f, 0.f, 0.f, 0.f, 0.f, 0.f};

    if (wsr < wer) {
        int last = wer - 1;
        for (int base = wsr; base < wer; base += 8) {
            int r0 = min(base + qg, last);
            int r1 = min(base + 4 + qg, last);
            float4 v0 = x4[(size_t)r0 * 16 + c];
            float4 v1 = x4[(size_t)r1 * 16 + c];
            const __half2* h0 = (const __half2*)&v0;
            const __half2* h1 = (const __half2*)&v1;
            float2 a0 = __half22float2(h0[0]), a1 = __half22float2(h0[1]);
            float2 a2 = __half22float2(h0[2]), a3 = __half22float2(h0[3]);
            float2 b0 = __half22float2(h1[0]), b1 = __half22float2(h1[1]);
            float2 b2 = __half22float2(h1[2]), b3 = __half22float2(h1[3]);
            float xf0[8] = {a0.x, a0.y, a1.x, a1.y, a2.x, a2.y, a3.x, a3.y};
            float xf1[8] = {b0.x, b0.y, b1.x, b1.y, b2.x, b2.y, b3.x, b3.y};

            float p0 = xf0[0] * q0.x + xf0[1] * q0.y + xf0[2] * q0.z + xf0[3] * q0.w
                     + xf0[4] * q1.x + xf0[5] * q1.y + xf0[6] * q1.z + xf0[7] * q1.w;
            float p1 = xf1[0] * q0.x + xf1[1] * q0.y + xf1[2] * q0.z + xf1[3] * q0.w
                     + xf1[4] * q1.x + xf1[5] * q1.y + xf1[6] * q1.z + xf1[7] * q1.w;
#pragma unroll
            for (int off = 1; off < 16; off <<= 1) {
                p0 += __shfl_xor(p0, off);
                p1 += __shfl_xor(p1, off);
            }
            float p0a = __shfl_xor(p0, 16), p0b = __shfl_xor(p0, 32), p0c = __shfl_xor(p0a, 32);
            float p1a = __shfl_xor(p1, 16), p1b = __shfl_xor(p1, 32), p1c = __shfl_xor(p1a, 32);
            float s00 = (base + qg       < wer) ? p0  : -INFINITY;
            float s01 = (base + (qg ^ 1) < wer) ? p0a : -INFINITY;
            float s02 = (base + (qg ^ 2) < wer) ? p0b : -INFINITY;
            float s03 = (base + (qg ^ 3) < wer) ? p0c : -INFINITY;
            float s10 = (base + 4 + qg       < wer) ? p1  : -INFINITY;
            float s11 = (base + 4 + (qg ^ 1) < wer) ? p1a : -INFINITY;
            float s12 = (base + 4 + (qg ^ 2) < wer) ? p1b : -INFINITY;
            float s13 = (base + 4 + (qg ^ 3) < wer) ? p1c : -INFINITY;

            float mn = fmaxf(fmaxf(fmaxf(s00, s01), fmaxf(s02, s03)),
                             fmaxf(fmaxf(s10, s11), fmaxf(s12, s13)));
            mn = fmaxf(m, mn);
            float al = __expf(m - mn);
            float w00 = __expf(s00 - mn), w01 = __expf(s01 - mn);
            float w02 = __expf(s02 - mn), w03 = __expf(s03 - mn);
            float w10 = __expf(s10 - mn), w11 = __expf(s11 - mn);
            float w12 = __expf(s12 - mn), w13 = __expf(s13 - mn);
            float sg = (w00 + w01) + (w02 + w03) + ((w10 + w11) + (w12 + w13));
            s = s * al + sg;
#pragma unroll
            for (int j = 0; j < 8; ++j)
                acc[j] = acc[j] * al + w00 * xf0[j] + w10 * xf1[j];
            m = mn;
        }
    }
#pragma unroll
    for (int j = 0; j < 8; ++j) {
        acc[j] += __shfl_xor(acc[j], 16);
        acc[j] += __shfl_xor(acc[j], 32);
    }
    if (lane == 0) { sm[wave] = m; ss[wave] = s; }
    if (qg == 0) {
#pragma unroll
        for (int j = 0; j < 8; ++j) sacc[wave][8 * c + j] = acc[j];
    }
    __syncthreads();

    if (tid < D) {
        float m0 = sm[0], m1 = sm[1], m2 = sm[2], m3 = sm[3];
        float mstar = fmaxf(fmaxf(m0, m1), fmaxf(m2, m3));
        float r = 0.f;
        if (mstar > -INFINITY) {
            float e0 = __expf(m0 - mstar), e1 = __expf(m1 - mstar);
            float e2 = __expf(m2 - mstar), e3 = __expf(m3 - mstar);
            float stot = ss[0] * e0 + ss[1] * e1 + ss[2] * e2 + ss[3] * e3;
            float at = sacc[0][tid] * e0 + sacc[1][tid] * e1
                     + sacc[2][tid] * e2 + sacc[3][tid] * e3;
            r = at / fmaxf(stot, 1e-16f);
        }
        r_out[(size_t)g * r_stride + tid] = r;
    }
}

// ---------------- gates GEMM: 64x64 tile, 4x4 micro-tile, KC=32 ----------------
__global__ __launch_bounds__(256) void gates_gemm_kernel(
    const float* __restrict__ A1, int sA1,
    const float* __restrict__ W1,
    const float* __restrict__ A2,
    const float* __restrict__ W2, int sW2,
    const float* __restrict__ bias,
    float* __restrict__ gates) {
    __shared__ float As[32][72];
    __shared__ float Ws[32][72];
    int t = threadIdx.x;
    int tx = t & 15, ty = t >> 4;
    int g0 = blockIdx.x * 64, j0 = blockIdx.y * 64;
    int lr = t & 63;
    int lk = (t >> 6) * 8;

    float acc[4][4];
#pragma unroll
    for (int i = 0; i < 4; ++i)
#pragma unroll
        for (int j = 0; j < 4; ++j) acc[i][j] = 0.f;

    for (int phase = 0; phase < 2; ++phase) {
        const float* A = phase ? A2 : A1;
        int sA = phase ? D : sA1;
        const float* W = phase ? W2 : W1;
        int sW = phase ? sW2 : D;
        for (int kk = 0; kk < D; kk += 32) {
            float4 a0 = *(const float4*)&A[(size_t)(g0 + lr) * sA + kk + lk];
            float4 a1 = *(const float4*)&A[(size_t)(g0 + lr) * sA + kk + lk + 4];
            float4 w0 = *(const float4*)&W[(size_t)(j0 + lr) * sW + kk + lk];
            float4 w1 = *(const float4*)&W[(size_t)(j0 + lr) * sW + kk + lk + 4];
            __syncthreads();
            As[lk + 0][lr] = a0.x; As[lk + 1][lr] = a0.y; As[lk + 2][lr] = a0.z; As[lk + 3][lr] = a0.w;
            As[lk + 4][lr] = a1.x; As[lk + 5][lr] = a1.y; As[lk + 6][lr] = a1.z; As[lk + 7][lr] = a1.w;
            Ws[lk + 0][lr] = w0.x; Ws[lk + 1][lr] = w0.y; Ws[lk + 2][lr] = w0.z; Ws[lk + 3][lr] = w0.w;
            Ws[lk + 4][lr] = w1.x; Ws[lk + 5][lr] = w1.y; Ws[lk + 6][lr] = w1.z; Ws[lk + 7][lr] = w1.w;
            __syncthreads();
#pragma unroll
            for (int k = 0; k < 32; ++k) {
                float4 av = *(const float4*)&As[k][ty * 4];
                float4 bv = *(const float4*)&Ws[k][tx * 4];
                float aa[4] = {av.x, av.y, av.z, av.w};
                float bb[4] = {bv.x, bv.y, bv.z, bv.w};
#pragma unroll
                for (int i = 0; i < 4; ++i)
#pragma unroll
                    for (int j = 0; j < 4; ++j)
                        acc[i][j] = fmaf(aa[i], bb[j], acc[i][j]);
            }
        }
    }
#pragma unroll
    for (int i = 0; i < 4; ++i) {
        size_t row = (size_t)(g0 + ty * 4 + i);
        int jb = j0 + tx * 4;
        float4 o;
        o.x = acc[i][0] + bias[jb + 0];
        o.y = acc[i][1] + bias[jb + 1];
        o.z = acc[i][2] + bias[jb + 2];
        o.w = acc[i][3] + bias[jb + 3];
        *(float4*)&gates[row * 512 + jb] = o;
    }
}

extern "C" void kernel_launch(void* const* d_in, const int* in_sizes, int n_in,
                              void* d_out, int out_size, void* d_ws, size_t ws_size,
                              hipStream_t stream) {
    const float* x      = (const float*)d_in[0];
    const float* W_ih   = (const float*)d_in[1];
    const float* W_hh   = (const float*)d_in[2];
    const float* b_ih   = (const float*)d_in[3];
    const float* b_hh   = (const float*)d_in[4];
    const int*   index  = (const int*)d_in[5];
    int N = in_sizes[5];
    int G = out_size / (2 * D);
    float* out = (float*)d_out;
    size_t totalx = (size_t)N * D;

    float* ws = (float*)d_ws;
    __half* xh    = (__half*)ws;                        // N*D halfs (= N*D/2 floats)
    float* Wc     = ws + totalx / 2;                    // 512*D
    float* b_sum  = Wc + 4 * D * D;                     // 512
    float* h1     = b_sum + 4 * D;                      // D
    float* c1     = h1 + D;                             // D
    float* r1     = c1 + D;                             // G*D
    float* h2     = r1 + (size_t)G * D;                 // G*D
    float* c2     = h2 + (size_t)G * D;                 // G*D
    float* r2     = c2 + (size_t)G * D;                 // G*D
    float* gatesb = r2 + (size_t)G * D;                 // G*4D
    int* seg_off  = (int*)(gatesb + (size_t)G * 4 * D); // G+1

    prep_kernel<<<274, 256, 0, stream>>>(W_ih, W_hh, b_ih, b_hh, index, N, G,
                                         Wc, seg_off, b_sum, h1, c1);

    // ---- step 1: attention over fp32 x (emits fp16 copy), q = h1 broadcast
    attn_first_kernel<<<G, 256, 0, stream>>>(x, xh, seg_off, h1, r1, G);

    // ---- step 2: gates GEMM -> fused cell + attention (q = h2)
    gates_gemm_kernel<<<dim3(G / 64, 8), 256, 0, stream>>>(
        h1, 0, Wc, r1, W_ih + D, 2 * D, b_sum, gatesb);
    attn_cell_kernel<<<G, 256, 0, stream>>>(
        xh, seg_off, gatesb, c1, 0, c2, h2, D, r2, D, G);

    // ---- step 3: gates GEMM -> fused cell + attention, write straight to out
    gates_gemm_kernel<<<dim3(G / 64, 8), 256, 0, stream>>>(
        h2, D, Wc, r2, W_ih + D, 2 * D, b_sum, gatesb);
    attn_cell_kernel<<<G, 256, 0, stream>>>(
        xh, seg_off, gatesb, c2, D, nullptr, out, 2 * D, out + D, 2 * D, G);
}

// Round 3
// 467.694 us; speedup vs baseline: 1.0554x; 1.0292x over previous
//
#include <hip/hip_runtime.h>
#include <hip/hip_fp16.h>
#include <math.h>

#define D 128

typedef float f4v __attribute__((ext_vector_type(4)));

__device__ __forceinline__ float sigmoidf_(float x) { return 1.f / (1.f + __expf(-x)); }

__device__ __forceinline__ float4 pack8_to_half8(const float* xf) {
    __half2 hh[4];
    hh[0] = __floats2half2_rn(xf[0], xf[1]);
    hh[1] = __floats2half2_rn(xf[2], xf[3]);
    hh[2] = __floats2half2_rn(xf[4], xf[5]);
    hh[3] = __floats2half2_rn(xf[6], xf[7]);
    return *(float4*)hh;
}

// ---------------- prep: WcatT | seg_off | b_sum,h1,c1 ----------------
// WcatT[k][j] (k<256 input dim, j<512 gate rows), layout [256][512]:
//   k<128 : W_ih[j][k] + W_hh[j][k]   (h part, Wc)
//   k>=128: W_ih[j][k]                (r part)
__global__ void prep_kernel(const float* __restrict__ W_ih, const float* __restrict__ W_hh,
                            const float* __restrict__ b_ih, const float* __restrict__ b_hh,
                            const int* __restrict__ idx, int N, int G,
                            float* __restrict__ WcatT, int* __restrict__ seg_off,
                            float* __restrict__ b_sum, float* __restrict__ h1,
                            float* __restrict__ c1) {
    int b = blockIdx.x, t = threadIdx.x;
    if (b < 256) {
        int k = b;
        for (int j = t; j < 512; j += 256) {
            float v = W_ih[(size_t)j * 256 + k];
            if (k < 128) v += W_hh[(size_t)j * 128 + k];
            WcatT[(size_t)k * 512 + j] = v;
        }
    } else if (b < 273) {
        int g = (b - 256) * 256 + t;
        if (g <= G) {
            int lo = 0, hi = N;
            while (lo < hi) {
                int mid = (lo + hi) >> 1;
                if (idx[mid] < g) lo = mid + 1; else hi = mid;
            }
            seg_off[g] = lo;
        }
    } else {
        for (int i = t; i < 4 * D; i += 256) b_sum[i] = b_ih[i] + b_hh[i];
        if (t < D) {
            float bi = b_ih[t] + b_hh[t];
            float bg = b_ih[2 * D + t] + b_hh[2 * D + t];
            float bo = b_ih[3 * D + t] + b_hh[3 * D + t];
            float c = sigmoidf_(bi) * tanhf(bg);
            c1[t] = c;
            h1[t] = sigmoidf_(bo) * tanhf(c);
        }
    }
}

// ---------------- shared online-softmax update for 8 rows ----------------
__device__ __forceinline__ void online8(const float (&xf0)[8], const float (&xf1)[8],
                                        const float4 q0, const float4 q1,
                                        int base, int wer, int qg,
                                        float& m, float& s, float (&acc)[8]) {
    float p0 = xf0[0] * q0.x + xf0[1] * q0.y + xf0[2] * q0.z + xf0[3] * q0.w
             + xf0[4] * q1.x + xf0[5] * q1.y + xf0[6] * q1.z + xf0[7] * q1.w;
    float p1 = xf1[0] * q0.x + xf1[1] * q0.y + xf1[2] * q0.z + xf1[3] * q0.w
             + xf1[4] * q1.x + xf1[5] * q1.y + xf1[6] * q1.z + xf1[7] * q1.w;
#pragma unroll
    for (int off = 1; off < 16; off <<= 1) {
        p0 += __shfl_xor(p0, off);
        p1 += __shfl_xor(p1, off);
    }
    float p0a = __shfl_xor(p0, 16), p0b = __shfl_xor(p0, 32), p0c = __shfl_xor(p0a, 32);
    float p1a = __shfl_xor(p1, 16), p1b = __shfl_xor(p1, 32), p1c = __shfl_xor(p1a, 32);
    float s00 = (base + qg       < wer) ? p0  : -INFINITY;
    float s01 = (base + (qg ^ 1) < wer) ? p0a : -INFINITY;
    float s02 = (base + (qg ^ 2) < wer) ? p0b : -INFINITY;
    float s03 = (base + (qg ^ 3) < wer) ? p0c : -INFINITY;
    float s10 = (base + 4 + qg       < wer) ? p1  : -INFINITY;
    float s11 = (base + 4 + (qg ^ 1) < wer) ? p1a : -INFINITY;
    float s12 = (base + 4 + (qg ^ 2) < wer) ? p1b : -INFINITY;
    float s13 = (base + 4 + (qg ^ 3) < wer) ? p1c : -INFINITY;

    float mn = fmaxf(fmaxf(fmaxf(s00, s01), fmaxf(s02, s03)),
                     fmaxf(fmaxf(s10, s11), fmaxf(s12, s13)));
    mn = fmaxf(m, mn);
    float al = __expf(m - mn);
    float w00 = __expf(s00 - mn), w01 = __expf(s01 - mn);
    float w02 = __expf(s02 - mn), w03 = __expf(s03 - mn);
    float w10 = __expf(s10 - mn), w11 = __expf(s11 - mn);
    float w12 = __expf(s12 - mn), w13 = __expf(s13 - mn);
    float sg = (w00 + w01) + (w02 + w03) + ((w10 + w11) + (w12 + w13));
    s = s * al + sg;
#pragma unroll
    for (int j = 0; j < 8; ++j)
        acc[j] = acc[j] * al + w00 * xf0[j] + w10 * xf1[j];
    m = mn;
}

// merge the 4 lane-groups and write r (16 lanes x 8 cols = full row)
__device__ __forceinline__ void attn_finish(float (&acc)[8], float s, int qg, int c,
                                            float* rdst, bool wr) {
#pragma unroll
    for (int j = 0; j < 8; ++j) {
        acc[j] += __shfl_xor(acc[j], 16);
        acc[j] += __shfl_xor(acc[j], 32);
    }
    if (wr && qg == 0) {
        float inv = 1.f / fmaxf(s, 1e-16f);
        float4 o0; o0.x = acc[0] * inv; o0.y = acc[1] * inv; o0.z = acc[2] * inv; o0.w = acc[3] * inv;
        float4 o1; o1.x = acc[4] * inv; o1.y = acc[5] * inv; o1.z = acc[6] * inv; o1.w = acc[7] * inv;
        *(float4*)&rdst[8 * c] = o0;
        *(float4*)&rdst[8 * c + 4] = o1;
    }
}

// step-1 attention: fp32 x (nontemporal), emits fp16 copy
__device__ __forceinline__ void attn_f32(const float* __restrict__ x, __half* __restrict__ xh,
                                         int start, int end, int qg, int c,
                                         const float* qrow, float* rdst, bool wr) {
    float4 q0 = *(const float4*)&qrow[8 * c];
    float4 q1 = *(const float4*)&qrow[8 * c + 4];
    float m = -INFINITY, s = 0.f;
    float acc[8] = {0.f, 0.f, 0.f, 0.f, 0.f, 0.f, 0.f, 0.f};
    const f4v* x4 = (const f4v*)x;     // 32 per fp32 row
    float4* xh4 = (float4*)xh;         // 16 per fp16 row
    if (start < end) {
        int last = end - 1;
        for (int base = start; base < end; base += 8) {
            int r0 = min(base + qg, last);
            int r1 = min(base + 4 + qg, last);
            f4v f00 = __builtin_nontemporal_load(&x4[(size_t)r0 * 32 + 2 * c]);
            f4v f01 = __builtin_nontemporal_load(&x4[(size_t)r0 * 32 + 2 * c + 1]);
            f4v f10 = __builtin_nontemporal_load(&x4[(size_t)r1 * 32 + 2 * c]);
            f4v f11 = __builtin_nontemporal_load(&x4[(size_t)r1 * 32 + 2 * c + 1]);
            float xf0[8] = {f00.x, f00.y, f00.z, f00.w, f01.x, f01.y, f01.z, f01.w};
            float xf1[8] = {f10.x, f10.y, f10.z, f10.w, f11.x, f11.y, f11.z, f11.w};
            xh4[(size_t)r0 * 16 + c] = pack8_to_half8(xf0);
            xh4[(size_t)r1 * 16 + c] = pack8_to_half8(xf1);
            online8(xf0, xf1, q0, q1, base, end, qg, m, s, acc);
        }
    }
    attn_finish(acc, s, qg, c, rdst, wr);
}

// steps-2,3 attention: fp16 x
__device__ __forceinline__ void attn_f16(const __half* __restrict__ xh,
                                         int start, int end, int qg, int c,
                                         const float* qrow, float* rdst, bool wr) {
    float4 q0 = *(const float4*)&qrow[8 * c];
    float4 q1 = *(const float4*)&qrow[8 * c + 4];
    float m = -INFINITY, s = 0.f;
    float acc[8] = {0.f, 0.f, 0.f, 0.f, 0.f, 0.f, 0.f, 0.f};
    const float4* x4 = (const float4*)xh;  // 16 per fp16 row
    if (start < end) {
        int last = end - 1;
        for (int base = start; base < end; base += 8) {
            int r0 = min(base + qg, last);
            int r1 = min(base + 4 + qg, last);
            float4 v0 = x4[(size_t)r0 * 16 + c];
            float4 v1 = x4[(size_t)r1 * 16 + c];
            const __half2* h0 = (const __half2*)&v0;
            const __half2* h1 = (const __half2*)&v1;
            float2 a0 = __half22float2(h0[0]), a1 = __half22float2(h0[1]);
            float2 a2 = __half22float2(h0[2]), a3 = __half22float2(h0[3]);
            float2 b0 = __half22float2(h1[0]), b1 = __half22float2(h1[1]);
            float2 b2 = __half22float2(h1[2]), b3 = __half22float2(h1[3]);
            float xf0[8] = {a0.x, a0.y, a1.x, a1.y, a2.x, a2.y, a3.x, a3.y};
            float xf1[8] = {b0.x, b0.y, b1.x, b1.y, b2.x, b2.y, b3.x, b3.y};
            online8(xf0, xf1, q0, q1, base, end, qg, m, s, acc);
        }
    }
    attn_finish(acc, s, qg, c, rdst, wr);
}

// ---------------- monolithic per-segment kernel ----------------
// Block owns 4 segments (wave w <-> segment gbase+w). All state (h,c,r,gates)
// lives in LDS; weights stream from L2 (WcatT, 512 KB, shared by all blocks).
__global__ __launch_bounds__(256, 4) void fused_kernel(
    const float* __restrict__ x, __half* __restrict__ xh,
    const int* __restrict__ seg_off, const float* __restrict__ WcatT,
    const float* __restrict__ b_sum, const float* __restrict__ h1,
    const float* __restrict__ c1, float* __restrict__ out, int G) {

    __shared__ float qs[4][256];   // per segment: [h(128) | r(128)]
    __shared__ float cL[4][128];   // cell state
    __shared__ float gl[4][512];   // gates
    __shared__ float bL[512];      // bias

    int tid = threadIdx.x;
    int w = tid >> 6, lane = tid & 63;
    int qg = lane >> 4, c = lane & 15;
    int gbase = blockIdx.x * 4;
    int g = gbase + w;
    bool valid = g < G;
    int start = 0, end = 0;
    if (valid) { start = seg_off[g]; end = seg_off[g + 1]; }

    for (int e = tid; e < 512; e += 256) bL[e] = b_sum[e];
    if (tid < 128) {
        float hv = h1[tid], cv = c1[tid];
#pragma unroll
        for (int s2 = 0; s2 < 4; ++s2) { qs[s2][tid] = hv; cL[s2][tid] = cv; }
    }
    __syncthreads();

    // j0 = this lane's pair of gate rows in the matvec (wave w owns rows w*128..+127)
    int j0 = w * 128 + 2 * lane;
    const float* wp = WcatT + j0;

    // ======== step 1: attention (fp32 x -> fp16 emit), q = h1 ========
    attn_f32(x, xh, start, end, qg, c, &qs[w][0], &qs[w][128], true);
    __syncthreads();

#pragma unroll 1
    for (int step = 0; step < 2; ++step) {
        // ---- matvec: gates[s][j] = sum_k WcatT[k][j] * qs[s][k] + b[j] ----
        float a0[4] = {0.f, 0.f, 0.f, 0.f};
        float a1[4] = {0.f, 0.f, 0.f, 0.f};
        for (int k = 0; k < 256; k += 4) {
            float qv[4][4];
            *(float4*)qv[0] = *(const float4*)&qs[0][k];
            *(float4*)qv[1] = *(const float4*)&qs[1][k];
            *(float4*)qv[2] = *(const float4*)&qs[2][k];
            *(float4*)qv[3] = *(const float4*)&qs[3][k];
#pragma unroll
            for (int dk = 0; dk < 4; ++dk) {
                float2 wv = *(const float2*)&wp[(size_t)(k + dk) * 512];
#pragma unroll
                for (int s2 = 0; s2 < 4; ++s2) {
                    a0[s2] = fmaf(qv[s2][dk], wv.x, a0[s2]);
                    a1[s2] = fmaf(qv[s2][dk], wv.y, a1[s2]);
                }
            }
        }
        float bx = bL[j0], by = bL[j0 + 1];
#pragma unroll
        for (int s2 = 0; s2 < 4; ++s2) {
            float2 o; o.x = a0[s2] + bx; o.y = a1[s2] + by;
            *(float2*)&gl[s2][j0] = o;
        }
        __syncthreads();

        // ---- LSTM cell (elementwise, 4 segs x 128 over 256 threads x 2) ----
        bool final_step = (step == 1);
#pragma unroll
        for (int r2 = 0; r2 < 2; ++r2) {
            int e = tid + 256 * r2;
            int s2 = e >> 7, k = e & 127;
            float ig = gl[s2][k];
            float fg = gl[s2][128 + k];
            float gg = gl[s2][256 + k];
            float og = gl[s2][384 + k];
            float cp = cL[s2][k];
            float cc = sigmoidf_(fg) * cp + sigmoidf_(ig) * tanhf(gg);
            float hh = sigmoidf_(og) * tanhf(cc);
            cL[s2][k] = cc;
            qs[s2][k] = hh;
            if (final_step && (gbase + s2) < G)
                out[(size_t)(gbase + s2) * 256 + k] = hh;   // h3 -> out[:, :128]
        }
        __syncthreads();

        // ---- attention with q = new h ----
        if (!final_step) {
            attn_f16(xh, start, end, qg, c, &qs[w][0], &qs[w][128], true);
        } else {
            float* rdst = valid ? (out + (size_t)g * 256 + 128) : (float*)&qs[w][128];
            attn_f16(xh, start, end, qg, c, &qs[w][0], rdst, valid); // r3 -> out[:,128:]
        }
        __syncthreads();
    }
}

extern "C" void kernel_launch(void* const* d_in, const int* in_sizes, int n_in,
                              void* d_out, int out_size, void* d_ws, size_t ws_size,
                              hipStream_t stream) {
    const float* x      = (const float*)d_in[0];
    const float* W_ih   = (const float*)d_in[1];
    const float* W_hh   = (const float*)d_in[2];
    const float* b_ih   = (const float*)d_in[3];
    const float* b_hh   = (const float*)d_in[4];
    const int*   index  = (const int*)d_in[5];
    int N = in_sizes[5];
    int G = out_size / (2 * D);
    float* out = (float*)d_out;
    size_t totalx = (size_t)N * D;

    float* ws = (float*)d_ws;
    __half* xh    = (__half*)ws;                        // N*D halfs
    float* WcatT  = ws + totalx / 2;                    // 256*512
    float* b_sum  = WcatT + 256 * 512;                  // 512
    float* h1     = b_sum + 4 * D;                      // 128
    float* c1     = h1 + D;                             // 128
    int* seg_off  = (int*)(c1 + D);                     // G+1

    prep_kernel<<<274, 256, 0, stream>>>(W_ih, W_hh, b_ih, b_hh, index, N, G,
                                         WcatT, seg_off, b_sum, h1, c1);

    int nb = (G + 3) >> 2;
    fused_kernel<<<nb, 256, 0, stream>>>(x, xh, seg_off, WcatT, b_sum, h1, c1, out, G);
}